// Round 4
// baseline (372.921 us; speedup 1.0000x reference)
//
#include <hip/hip_runtime.h>
#include <stdint.h>

// ---------------- constants ----------------
#define NCLS 20
#define STG_PER_WAVE 640
#define STG_TRIG 512
#define SURV_CAP 2048

__device__ __forceinline__ float sigm(float x) { return 1.0f / (1.0f + expf(-x)); }

// ---------------- K0: init ws ----------------
__global__ void k_init(unsigned int* hdr, unsigned int* hist) {
    int t = threadIdx.x;
    for (int i = t; i < 64; i += 1024) hdr[i] = 0u;
    for (int i = t; i < 3 * 4096; i += 1024) hist[i] = 0u;
}

// ---------------- K1/K2: streaming score pass ----------------
// hdr[0..2] : main-pass append counts per level
// hdr[4..6] : fallback append counts per level
// Block = 512 pixels x 1 anchor (obj + 20 cls channels), 256 thr x 2 px (float2).
// L0: 200x3=600 blocks; L1: 50x3=150; L2: 13x3=39. Total 789.
template<int FB>
__global__ __launch_bounds__(256) void k_score(
    const float* __restrict__ obj0, const float* __restrict__ cls0,
    const float* __restrict__ obj1, const float* __restrict__ cls1,
    const float* __restrict__ obj2, const float* __restrict__ cls2,
    unsigned int* hdr, unsigned int* hist,
    unsigned long long* buf0, unsigned long long* buf1, unsigned long long* buf2,
    int cap0, int cap1, int cap2)
{
    int b = blockIdx.x;
    int L, tile, a, W;
    const float *obj, *cls; unsigned long long* gbuf; int cap;
    if (b < 600)      { L = 0; tile = b % 200;              a = b / 200; W = 320; obj = obj0; cls = cls0; gbuf = buf0; cap = cap0; }
    else if (b < 750) { int bb = b - 600; L = 1; tile = bb % 50; a = bb / 50; W = 160; obj = obj1; cls = cls1; gbuf = buf1; cap = cap1; }
    else              { int bb = b - 750; L = 2; tile = bb % 13; a = bb / 13; W = 80;  obj = obj2; cls = cls2; gbuf = buf2; cap = cap2; }
    const int P = W * W;
    if (FB) { if (hdr[L] >= 100u) return; }   // fallback not needed for this level

    __shared__ unsigned long long stage[4 * STG_PER_WAVE];
    __shared__ unsigned int lhist[4096];
    __shared__ int wcnt[4];

    const int t = threadIdx.x;
    const int wid = t >> 6, lane = t & 63;
    for (int i = t; i < 4096; i += 256) lhist[i] = 0u;
    if (lane == 0) wcnt[wid] = 0;
    __syncthreads();

    unsigned long long* wstage = stage + wid * STG_PER_WAVE;

    const int p0 = tile * 512 + t * 2;       // 2 pixels/thread; P even for all levels
    const bool act = p0 < P;

    float so0 = 0.f, so1 = 0.f;
    if (act) {
        float2 ov = *(const float2*)(obj + (size_t)a * P + p0);
        so0 = sigm(ov.x); so1 = sigm(ov.y);
    }
    #pragma unroll
    for (int c = 0; c < NCLS; c++) {
        if (act) {
            float2 cv = *(const float2*)(cls + (size_t)(a * NCLS + c) * P + p0);
            float s0 = so0 * sigm(cv.x);
            float s1 = so1 * sigm(cv.y);
            #pragma unroll
            for (int q = 0; q < 2; q++) {
                float s = q ? s1 : s0;
                unsigned int bits = __float_as_uint(s);
                if (!FB && s >= 0.5f) {   // histogram only in main pass
                    unsigned int bin = (bits - 0x3F000000u) >> 11;
                    if (bin > 4095u) bin = 4095u;
                    atomicAdd(&lhist[bin], 1u);
                }
                bool take = FB ? (s <= 0.7f) : (s > 0.7f);
                if (take) {
                    unsigned int ti = (unsigned int)(((p0 + q) * 3 + a) * NCLS + c);
                    unsigned long long key =
                        ((unsigned long long)bits << 32) | (unsigned long long)(0xFFFFFFFFu - ti);
                    int pos = atomicAdd(&wcnt[wid], 1);
                    if (pos < STG_PER_WAVE) wstage[pos] = key;
                }
            }
        }
        // wave-uniform flush (max growth/check = 128; trigger 512, cap 640)
        if (wcnt[wid] >= STG_TRIG) {
            int n = wcnt[wid]; if (n > STG_PER_WAVE) n = STG_PER_WAVE;
            unsigned int base = 0;
            if (lane == 0) {
                if (FB) base = hdr[L] + atomicAdd(&hdr[4 + L], (unsigned int)n);
                else    base = atomicAdd(&hdr[L], (unsigned int)n);
            }
            base = __shfl(base, 0);
            for (int i = lane; i < n; i += 64) {
                unsigned int gp = base + i;
                if (gp < (unsigned int)cap) gbuf[gp] = wstage[i];
            }
            if (lane == 0) wcnt[wid] = 0;
        }
    }
    // final wave flush
    {
        int n = wcnt[wid]; if (n > STG_PER_WAVE) n = STG_PER_WAVE;
        if (n > 0) {
            unsigned int base = 0;
            if (lane == 0) {
                if (FB) base = hdr[L] + atomicAdd(&hdr[4 + L], (unsigned int)n);
                else    base = atomicAdd(&hdr[L], (unsigned int)n);
            }
            base = __shfl(base, 0);
            for (int i = lane; i < n; i += 64) {
                unsigned int gp = base + i;
                if (gp < (unsigned int)cap) gbuf[gp] = wstage[i];
            }
        }
    }
    if (!FB) {
        __syncthreads();
        for (int i = t; i < 4096; i += 256) {
            unsigned int v = lhist[i];
            if (v) atomicAdd(&hist[L * 4096 + i], v);
        }
    }
}

// ---------------- K_tail: scan + compact + select + decode + sort + NMS + out ----------------
__global__ __launch_bounds__(512) void k_tail(
    const unsigned int* __restrict__ hdr, const unsigned int* __restrict__ hist,
    const unsigned long long* __restrict__ buf0,
    const unsigned long long* __restrict__ buf1,
    const unsigned long long* __restrict__ buf2,
    int cap0, int cap1, int cap2,
    const float* __restrict__ reg0, const float* __restrict__ reg1, const float* __restrict__ reg2,
    float* __restrict__ out)
{
    const int t = threadIdx.x;
    __shared__ unsigned long long svl[SURV_CAP];          // 16 KB
    __shared__ unsigned long long topk[300];
    __shared__ unsigned int tsel[3];
    __shared__ int scnt;
    __shared__ float bx[300][4];
    __shared__ float sc[300];
    __shared__ int   lb[300];
    __shared__ unsigned long long key2[300];
    __shared__ float sbx[300][4];
    __shared__ float ssc[300];
    __shared__ int   slb[300];
    __shared__ float sar[300];
    __shared__ unsigned long long supmat[300][5];
    __shared__ unsigned char keepA[300];

    for (int i = t; i < 300; i += 512) topk[i] = 0ull;
    if (t < 3) tsel[t] = 0u;
    __syncthreads();

    // ---- phase A: histogram suffix scan -> per-level selection threshold (3 waves) ----
    if (t < 192) {
        int L = t >> 6, lane = t & 63;
        const unsigned int* h = hist + L * 4096;
        unsigned int s = 0;
        #pragma clang loop unroll(disable)
        for (int k = 0; k < 64; k++) s += h[4095 - (lane * 64 + k)];
        unsigned int incl = s;
        #pragma unroll
        for (int off = 1; off < 64; off <<= 1) {
            unsigned int u = __shfl_up(incl, off);
            if (lane >= off) incl += u;
        }
        unsigned int excl = incl - s;
        if (excl < 100u && incl >= 100u) {
            unsigned int cum = excl;
            #pragma clang loop unroll(disable)
            for (int k = 0; k < 64; k++) {
                cum += h[4095 - (lane * 64 + k)];
                if (cum >= 100u) {
                    tsel[L] = 0x3F000000u + ((unsigned int)(4095 - (lane * 64 + k)) << 11);
                    break;
                }
            }
        }
    }
    __syncthreads();

    // ---- phase B: per level, compact buffer -> svl (LDS), rank-select -> topk ----
    const int lane = t & 63;
    for (int L = 0; L < 3; L++) {
        if (t == 0) scnt = 0;
        __syncthreads();
        const unsigned long long* buf = (L == 0) ? buf0 : (L == 1 ? buf1 : buf2);
        int cap = (L == 0) ? cap0 : (L == 1 ? cap1 : cap2);
        unsigned int cnt = hdr[L] + hdr[4 + L];
        int n = (int)((cnt < (unsigned int)cap) ? cnt : (unsigned int)cap);
        unsigned int ts = tsel[L];
        #pragma clang loop unroll(disable)
        for (int i = t; i < n; i += 512) {
            unsigned long long k = buf[i];
            bool takeIt = (unsigned int)(k >> 32) >= ts;
            unsigned long long m = __ballot(takeIt);
            if (takeIt) {
                int lead = __ffsll((long long)m) - 1;
                int pref = __popcll(m & ((1ull << lane) - 1ull));
                int base = 0;
                if (lane == lead) base = atomicAdd(&scnt, (int)__popcll(m));
                base = __shfl(base, lead);
                int pos = base + pref;
                if (pos < SURV_CAP) svl[pos] = k;
            }
        }
        __syncthreads();
        int n2 = scnt; if (n2 > SURV_CAP) n2 = SURV_CAP;
        #pragma clang loop unroll(disable)
        for (int i = t; i < n2; i += 512) {
            unsigned long long ki = svl[i];
            int r = 0;
            #pragma clang loop unroll(disable)
            for (int j = 0; j < n2; j++) r += (svl[j] > ki);
            if (r < 100) topk[L * 100 + r] = ki;
        }
        __syncthreads();
    }

    // ---- phase C: decode boxes for the 300 selected ----
    const int   Wl[3] = {320, 160, 80};
    const float Sl[3] = {8.f, 16.f, 32.f};
    const float AW[3][3] = {{12.f, 19.f, 40.f}, {36.f, 76.f, 72.f}, {142.f, 192.f, 459.f}};
    const float AH[3][3] = {{16.f, 36.f, 28.f}, {75.f, 55.f, 146.f}, {110.f, 243.f, 401.f}};

    for (int i = t; i < 300; i += 512) {
        unsigned long long k = topk[i];
        int L = i / 100;
        float s = __uint_as_float((unsigned int)(k >> 32));
        unsigned int ti = 0xFFFFFFFFu - (unsigned int)k;
        float x1 = 0.f, y1 = 0.f, x2 = 0.f, y2 = 0.f; int c = 0;
        if (k != 0ull) {
            c = (int)(ti % NCLS);
            unsigned int na = ti / NCLS;
            int a = (int)(na % 3);
            int p = (int)(na / 3);
            int W = Wl[L]; int P = W * W;
            int px = p % W, py = p / W;
            const float* reg = (L == 0) ? reg0 : (L == 1 ? reg1 : reg2);
            float tx = reg[(a * 4 + 0) * P + p];
            float ty = reg[(a * 4 + 1) * P + p];
            float tw = reg[(a * 4 + 2) * P + p];
            float th = reg[(a * 4 + 3) * P + p];
            float st = Sl[L];
            float cx = (sigm(tx) * 3.0f - 1.5f + ((float)px + 0.5f)) * st;
            float cy = (sigm(ty) * 3.0f - 1.5f + ((float)py + 0.5f)) * st;
            float w = expf(tw) * AW[L][a];
            float h = expf(th) * AH[L][a];
            x1 = cx - 0.5f * w; y1 = cy - 0.5f * h; x2 = cx + 0.5f * w; y2 = cy + 0.5f * h;
        } else {
            s = 0.f;
        }
        bx[i][0] = x1; bx[i][1] = y1; bx[i][2] = x2; bx[i][3] = y2;
        sc[i] = s; lb[i] = c;
        // stable argsort(-scores): score desc, concat-position asc
        key2[i] = (k & 0xFFFFFFFF00000000ull) | (unsigned long long)(299 - i);
    }
    __syncthreads();

    // ---- phase D: sort the 300 by rank ----
    for (int i = t; i < 300; i += 512) {
        unsigned long long ki = key2[i];
        int r = 0;
        #pragma clang loop unroll(disable)
        for (int j = 0; j < 300; j++) r += (key2[j] > ki);
        sbx[r][0] = bx[i][0]; sbx[r][1] = bx[i][1]; sbx[r][2] = bx[i][2]; sbx[r][3] = bx[i][3];
        ssc[r] = sc[i]; slb[r] = lb[i];
    }
    __syncthreads();
    for (int i = t; i < 300; i += 512)
        sar[i] = (sbx[i][2] - sbx[i][0]) * (sbx[i][3] - sbx[i][1]);
    __syncthreads();

    // ---- phase E: suppression matrix rows as bitmasks ----
    for (int i = t; i < 300; i += 512) {
        float ax1 = sbx[i][0], ay1 = sbx[i][1], ax2 = sbx[i][2], ay2 = sbx[i][3], aa = sar[i];
        int al = slb[i];
        unsigned long long wds[5] = {0ull, 0ull, 0ull, 0ull, 0ull};
        #pragma unroll
        for (int w = 0; w < 5; w++) {
            unsigned long long acc = 0ull;
            int jbase = w * 64;
            int jend = (w == 4) ? 44 : 64;
            #pragma clang loop unroll(disable)
            for (int jb = 0; jb < jend; jb++) {
                int j = jbase + jb;
                float xx1 = fmaxf(ax1, sbx[j][0]);
                float yy1 = fmaxf(ay1, sbx[j][1]);
                float xx2 = fminf(ax2, sbx[j][2]);
                float yy2 = fminf(ay2, sbx[j][3]);
                float iw = fmaxf(1e-10f, xx2 - xx1);
                float ih = fmaxf(1e-10f, yy2 - yy1);
                float inter = iw * ih;
                float iou = inter / (aa + sar[j] - inter);
                if (iou > 0.5f && al == slb[j]) acc |= (1ull << jb);
            }
            wds[w] = acc;
        }
        #pragma unroll
        for (int w = 0; w < 5; w++) supmat[i][w] = wds[w];
    }
    __syncthreads();

    // ---- phase F: greedy NMS, wave 0, register state, NO unroll ----
    if (t < 64) {
        const int l = t;
        unsigned long long v0 = __ballot(ssc[l]       > 0.01f);
        unsigned long long v1 = __ballot(ssc[64 + l]  > 0.01f);
        unsigned long long v2 = __ballot(ssc[128 + l] > 0.01f);
        unsigned long long v3 = __ballot(ssc[192 + l] > 0.01f);
        unsigned long long v4 = __ballot((256 + l) < 300 ? (ssc[256 + l] > 0.01f) : false);

        unsigned long long s0 = 0, s1 = 0, s2 = 0, s3 = 0, s4 = 0;
        unsigned long long k0 = 0, k1 = 0, k2 = 0, k3 = 0, k4 = 0;
        unsigned long long rA0 = supmat[0][0], rA1 = supmat[0][1], rA2 = supmat[0][2],
                           rA3 = supmat[0][3], rA4 = supmat[0][4];
        #pragma clang loop unroll(disable)
        for (int i = 0; i < 300; i++) {
            unsigned long long rB0 = 0, rB1 = 0, rB2 = 0, rB3 = 0, rB4 = 0;
            if (i + 1 < 300) {
                rB0 = supmat[i + 1][0]; rB1 = supmat[i + 1][1]; rB2 = supmat[i + 1][2];
                rB3 = supmat[i + 1][3]; rB4 = supmat[i + 1][4];
            }
            int w = i >> 6, b = i & 63;
            unsigned long long sw = (w == 0) ? s0 : (w == 1) ? s1 : (w == 2) ? s2 : (w == 3) ? s3 : s4;
            unsigned long long vw = (w == 0) ? v0 : (w == 1) ? v1 : (w == 2) ? v2 : (w == 3) ? v3 : v4;
            bool kept = (((sw >> b) & 1ull) == 0ull) && (((vw >> b) & 1ull) != 0ull);
            unsigned long long kb = kept ? (1ull << b) : 0ull;
            k0 |= (w == 0) ? kb : 0ull; k1 |= (w == 1) ? kb : 0ull; k2 |= (w == 2) ? kb : 0ull;
            k3 |= (w == 3) ? kb : 0ull; k4 |= (w == 4) ? kb : 0ull;
            unsigned long long tail = (b == 63) ? 0ull : ((~0ull) << (b + 1));
            unsigned long long e = kept ? ~0ull : 0ull;
            s0 |= rA0 & e & ((w == 0) ? tail : 0ull);
            s1 |= rA1 & e & ((w == 1) ? tail : ((w < 1) ? ~0ull : 0ull));
            s2 |= rA2 & e & ((w == 2) ? tail : ((w < 2) ? ~0ull : 0ull));
            s3 |= rA3 & e & ((w == 3) ? tail : ((w < 3) ? ~0ull : 0ull));
            s4 |= rA4 & e & ((w == 4) ? tail : ((w < 4) ? ~0ull : 0ull));
            rA0 = rB0; rA1 = rB1; rA2 = rB2; rA3 = rB3; rA4 = rB4;
        }
        keepA[l]       = (unsigned char)((k0 >> l) & 1ull);
        keepA[64 + l]  = (unsigned char)((k1 >> l) & 1ull);
        keepA[128 + l] = (unsigned char)((k2 >> l) & 1ull);
        keepA[192 + l] = (unsigned char)((k3 >> l) & 1ull);
        if (256 + l < 300) keepA[256 + l] = (unsigned char)((k4 >> l) & 1ull);
    }
    __syncthreads();

    // ---- phase G: outputs ----
    for (int i = t; i < 300; i += 512) {
        out[i * 4 + 0] = sbx[i][0];
        out[i * 4 + 1] = sbx[i][1];
        out[i * 4 + 2] = sbx[i][2];
        out[i * 4 + 3] = sbx[i][3];
        float kp = keepA[i] ? 1.f : 0.f;
        out[1200 + i] = ssc[i] * kp;
        out[1500 + i] = (float)slb[i];
        out[1800 + i] = kp;
    }
}

// ---------------- launch ----------------
extern "C" void kernel_launch(void* const* d_in, const int* in_sizes, int n_in,
                              void* d_out, int out_size, void* d_ws, size_t ws_size,
                              hipStream_t stream)
{
    const float* obj0 = (const float*)d_in[0];
    const float* cls0 = (const float*)d_in[1];
    const float* reg0 = (const float*)d_in[2];
    const float* obj1 = (const float*)d_in[3];
    const float* cls1 = (const float*)d_in[4];
    const float* reg1 = (const float*)d_in[5];
    const float* obj2 = (const float*)d_in[6];
    const float* cls2 = (const float*)d_in[7];
    const float* reg2 = (const float*)d_in[8];

    char* ws = (char*)d_ws;
    unsigned int* hdr  = (unsigned int*)ws;                       // 256 B
    unsigned int* hist = (unsigned int*)(ws + 256);               // 48 KB
    const size_t off = 131072;

    size_t avail = (ws_size > off) ? (ws_size - off) : 0;
    long long ents = (long long)(avail / 8);
    long long cap0 = ents * 16 / 21; if (cap0 > 6144000LL) cap0 = 6144000LL;
    long long cap1 = ents * 4 / 21;  if (cap1 > 1536000LL) cap1 = 1536000LL;
    long long cap2 = ents * 1 / 21;  if (cap2 > 384000LL)  cap2 = 384000LL;
    if (cap0 < 1) cap0 = 1; if (cap1 < 1) cap1 = 1; if (cap2 < 1) cap2 = 1;

    unsigned long long* buf0 = (unsigned long long*)(ws + off);
    unsigned long long* buf1 = buf0 + cap0;
    unsigned long long* buf2 = buf1 + cap1;

    k_init<<<1, 1024, 0, stream>>>(hdr, hist);
    k_score<0><<<789, 256, 0, stream>>>(obj0, cls0, obj1, cls1, obj2, cls2,
                                        hdr, hist, buf0, buf1, buf2,
                                        (int)cap0, (int)cap1, (int)cap2);
    k_score<1><<<789, 256, 0, stream>>>(obj0, cls0, obj1, cls1, obj2, cls2,
                                        hdr, hist, buf0, buf1, buf2,
                                        (int)cap0, (int)cap1, (int)cap2);
    k_tail<<<1, 512, 0, stream>>>(hdr, hist, buf0, buf1, buf2,
                                  (int)cap0, (int)cap1, (int)cap2,
                                  reg0, reg1, reg2, (float*)d_out);
}

// Round 5
// 251.146 us; speedup vs baseline: 1.4849x; 1.4849x over previous
//
#include <hip/hip_runtime.h>
#include <stdint.h>

// ---------------- constants ----------------
#define NCLS 20
#define STG_PER_WAVE 640
#define STG_TRIG 512
#define SURV_CAP 2048

__device__ __forceinline__ float sigm(float x) { return 1.0f / (1.0f + expf(-x)); }

// ---------------- K0: init ws ----------------
__global__ void k_init(unsigned int* hdr, unsigned int* hist) {
    int t = threadIdx.x;
    for (int i = t; i < 64; i += 1024) hdr[i] = 0u;
    for (int i = t; i < 3 * 4096; i += 1024) hist[i] = 0u;
}

// ---------------- K1/K2: streaming score pass ----------------
// hdr[0..2] main counts, hdr[4..6] fallback counts, hdr[8..10] Tsel, hdr[12..14] survivors
template<int FB>
__global__ __launch_bounds__(256) void k_score(
    const float* __restrict__ obj0, const float* __restrict__ cls0,
    const float* __restrict__ obj1, const float* __restrict__ cls1,
    const float* __restrict__ obj2, const float* __restrict__ cls2,
    unsigned int* hdr, unsigned int* hist,
    unsigned long long* buf0, unsigned long long* buf1, unsigned long long* buf2,
    int cap0, int cap1, int cap2)
{
    int b = blockIdx.x;
    int L, tile, a, W;
    const float *obj, *cls; unsigned long long* gbuf; int cap;
    if (b < 600)      { L = 0; tile = b % 200;              a = b / 200; W = 320; obj = obj0; cls = cls0; gbuf = buf0; cap = cap0; }
    else if (b < 750) { int bb = b - 600; L = 1; tile = bb % 50; a = bb / 50; W = 160; obj = obj1; cls = cls1; gbuf = buf1; cap = cap1; }
    else              { int bb = b - 750; L = 2; tile = bb % 13; a = bb / 13; W = 80;  obj = obj2; cls = cls2; gbuf = buf2; cap = cap2; }
    const int P = W * W;
    if (FB) { if (hdr[L] >= 100u) return; }

    __shared__ unsigned long long stage[4 * STG_PER_WAVE];
    __shared__ unsigned int lhist[4096];
    __shared__ int wcnt[4];

    const int t = threadIdx.x;
    const int wid = t >> 6, lane = t & 63;
    for (int i = t; i < 4096; i += 256) lhist[i] = 0u;
    if (lane == 0) wcnt[wid] = 0;
    __syncthreads();

    unsigned long long* wstage = stage + wid * STG_PER_WAVE;
    const int p0 = tile * 512 + t * 2;
    const bool act = p0 < P;

    float so0 = 0.f, so1 = 0.f;
    if (act) {
        float2 ov = *(const float2*)(obj + (size_t)a * P + p0);
        so0 = sigm(ov.x); so1 = sigm(ov.y);
    }
    #pragma unroll
    for (int c = 0; c < NCLS; c++) {
        if (act) {
            float2 cv = *(const float2*)(cls + (size_t)(a * NCLS + c) * P + p0);
            float s0 = so0 * sigm(cv.x);
            float s1 = so1 * sigm(cv.y);
            #pragma unroll
            for (int q = 0; q < 2; q++) {
                float s = q ? s1 : s0;
                unsigned int bits = __float_as_uint(s);
                if (!FB && s >= 0.5f) {
                    unsigned int bin = (bits - 0x3F000000u) >> 11;
                    if (bin > 4095u) bin = 4095u;
                    atomicAdd(&lhist[bin], 1u);
                }
                bool take = FB ? (s <= 0.7f) : (s > 0.7f);
                if (take) {
                    unsigned int ti = (unsigned int)(((p0 + q) * 3 + a) * NCLS + c);
                    unsigned long long key =
                        ((unsigned long long)bits << 32) | (unsigned long long)(0xFFFFFFFFu - ti);
                    int pos = atomicAdd(&wcnt[wid], 1);
                    if (pos < STG_PER_WAVE) wstage[pos] = key;
                }
            }
        }
        if (wcnt[wid] >= STG_TRIG) {      // wave-uniform flush
            int n = wcnt[wid]; if (n > STG_PER_WAVE) n = STG_PER_WAVE;
            unsigned int base = 0;
            if (lane == 0) {
                if (FB) base = hdr[L] + atomicAdd(&hdr[4 + L], (unsigned int)n);
                else    base = atomicAdd(&hdr[L], (unsigned int)n);
            }
            base = __shfl(base, 0);
            for (int i = lane; i < n; i += 64) {
                unsigned int gp = base + i;
                if (gp < (unsigned int)cap) gbuf[gp] = wstage[i];
            }
            if (lane == 0) wcnt[wid] = 0;
        }
    }
    {   // final flush
        int n = wcnt[wid]; if (n > STG_PER_WAVE) n = STG_PER_WAVE;
        if (n > 0) {
            unsigned int base = 0;
            if (lane == 0) {
                if (FB) base = hdr[L] + atomicAdd(&hdr[4 + L], (unsigned int)n);
                else    base = atomicAdd(&hdr[L], (unsigned int)n);
            }
            base = __shfl(base, 0);
            for (int i = lane; i < n; i += 64) {
                unsigned int gp = base + i;
                if (gp < (unsigned int)cap) gbuf[gp] = wstage[i];
            }
        }
    }
    if (!FB) {
        __syncthreads();
        for (int i = t; i < 4096; i += 256) {
            unsigned int v = lhist[i];
            if (v) atomicAdd(&hist[L * 4096 + i], v);
        }
    }
}

// ---------------- K3: threshold select (3 waves) ----------------
__global__ void k_scan(unsigned int* hdr, const unsigned int* __restrict__ hist) {
    int t = threadIdx.x;
    int L = t >> 6, lane = t & 63;
    if (L >= 3) return;
    const unsigned int* h = hist + L * 4096;
    unsigned int s = 0;
    #pragma clang loop unroll(disable)
    for (int k = 0; k < 64; k++) s += h[4095 - (lane * 64 + k)];
    unsigned int incl = s;
    #pragma unroll
    for (int off = 1; off < 64; off <<= 1) {
        unsigned int u = __shfl_up(incl, off);
        if (lane >= off) incl += u;
    }
    unsigned int excl = incl - s;
    if (excl < 100u && incl >= 100u) {
        unsigned int cum = excl;
        #pragma clang loop unroll(disable)
        for (int k = 0; k < 64; k++) {
            cum += h[4095 - (lane * 64 + k)];
            if (cum >= 100u) {
                hdr[8 + L] = 0x3F000000u + ((unsigned int)(4095 - (lane * 64 + k)) << 11);
                break;
            }
        }
    }
}

// ---------------- K4: parallel compact (>= Tsel) ----------------
__global__ __launch_bounds__(256) void k_compact(unsigned int* hdr,
                          const unsigned long long* __restrict__ buf0,
                          const unsigned long long* __restrict__ buf1,
                          const unsigned long long* __restrict__ buf2,
                          int cap0, int cap1, int cap2,
                          unsigned long long* surv)
{
    int gt = blockIdx.x * blockDim.x + threadIdx.x;
    int gstep = gridDim.x * blockDim.x;
    int lane = threadIdx.x & 63;
    for (int L = 0; L < 3; L++) {
        const unsigned long long* buf = (L == 0) ? buf0 : (L == 1 ? buf1 : buf2);
        int cap = (L == 0) ? cap0 : (L == 1 ? cap1 : cap2);
        unsigned int cnt = hdr[L] + hdr[4 + L];
        int n = (int)((cnt < (unsigned int)cap) ? cnt : (unsigned int)cap);
        unsigned int ts = hdr[8 + L];
        #pragma clang loop unroll(disable)
        for (int i = gt; i < n; i += gstep) {
            unsigned long long k = buf[i];
            bool takeIt = (unsigned int)(k >> 32) >= ts;
            unsigned long long m = __ballot(takeIt);
            if (takeIt) {
                int lead = __ffsll((long long)m) - 1;
                int pref = __popcll(m & ((1ull << lane) - 1ull));
                unsigned int base = 0;
                if (lane == lead) base = atomicAdd(&hdr[12 + L], (unsigned int)__popcll(m));
                base = __shfl(base, lead);
                unsigned int pos = base + (unsigned int)pref;
                if (pos < SURV_CAP) surv[L * SURV_CAP + pos] = k;
            }
        }
    }
}

// ---------------- K5: rank-select + decode + sort + supmat ----------------
// Writes: sortf[300][8] = {x1,y1,x2,y2,score,label, -, -} and supG[300][5] bitmask rows.
__global__ __launch_bounds__(512) void k_rank(
    const unsigned int* __restrict__ hdr,
    const unsigned long long* __restrict__ surv,
    const float* __restrict__ reg0, const float* __restrict__ reg1, const float* __restrict__ reg2,
    float* __restrict__ sortf, unsigned long long* __restrict__ supG)
{
    const int t = threadIdx.x;
    __shared__ unsigned long long svl[SURV_CAP];
    __shared__ unsigned long long topk[300];
    __shared__ float bx[300][4];
    __shared__ float sc[300];
    __shared__ int   lb[300];
    __shared__ unsigned long long key2[300];
    __shared__ float sbx[300][4];
    __shared__ float ssc[300];
    __shared__ int   slb[300];
    __shared__ float sar[300];

    for (int i = t; i < 300; i += 512) topk[i] = 0ull;
    __syncthreads();

    // rank-select per level (keys unique)
    for (int L = 0; L < 3; L++) {
        int n = (int)hdr[12 + L]; if (n > SURV_CAP) n = SURV_CAP;
        const unsigned long long* sv = surv + L * SURV_CAP;
        for (int i = t; i < n; i += 512) svl[i] = sv[i];
        __syncthreads();
        #pragma clang loop unroll(disable)
        for (int i = t; i < n; i += 512) {
            unsigned long long ki = svl[i];
            int r = 0;
            #pragma clang loop unroll(disable)
            for (int j = 0; j < n; j++) r += (svl[j] > ki);
            if (r < 100) topk[L * 100 + r] = ki;
        }
        __syncthreads();
    }

    const int   Wl[3] = {320, 160, 80};
    const float Sl[3] = {8.f, 16.f, 32.f};
    const float AW[3][3] = {{12.f, 19.f, 40.f}, {36.f, 76.f, 72.f}, {142.f, 192.f, 459.f}};
    const float AH[3][3] = {{16.f, 36.f, 28.f}, {75.f, 55.f, 146.f}, {110.f, 243.f, 401.f}};

    // decode
    for (int i = t; i < 300; i += 512) {
        unsigned long long k = topk[i];
        int L = i / 100;
        float s = __uint_as_float((unsigned int)(k >> 32));
        unsigned int ti = 0xFFFFFFFFu - (unsigned int)k;
        float x1 = 0.f, y1 = 0.f, x2 = 0.f, y2 = 0.f; int c = 0;
        if (k != 0ull) {
            c = (int)(ti % NCLS);
            unsigned int na = ti / NCLS;
            int a = (int)(na % 3);
            int p = (int)(na / 3);
            int W = Wl[L]; int P = W * W;
            int px = p % W, py = p / W;
            const float* reg = (L == 0) ? reg0 : (L == 1 ? reg1 : reg2);
            float tx = reg[(a * 4 + 0) * P + p];
            float ty = reg[(a * 4 + 1) * P + p];
            float tw = reg[(a * 4 + 2) * P + p];
            float th = reg[(a * 4 + 3) * P + p];
            float st = Sl[L];
            float cx = (sigm(tx) * 3.0f - 1.5f + ((float)px + 0.5f)) * st;
            float cy = (sigm(ty) * 3.0f - 1.5f + ((float)py + 0.5f)) * st;
            float w = expf(tw) * AW[L][a];
            float h = expf(th) * AH[L][a];
            x1 = cx - 0.5f * w; y1 = cy - 0.5f * h; x2 = cx + 0.5f * w; y2 = cy + 0.5f * h;
        } else {
            s = 0.f;
        }
        bx[i][0] = x1; bx[i][1] = y1; bx[i][2] = x2; bx[i][3] = y2;
        sc[i] = s; lb[i] = c;
        key2[i] = (k & 0xFFFFFFFF00000000ull) | (unsigned long long)(299 - i);  // stable
    }
    __syncthreads();

    // sort by rank
    for (int i = t; i < 300; i += 512) {
        unsigned long long ki = key2[i];
        int r = 0;
        #pragma clang loop unroll(disable)
        for (int j = 0; j < 300; j++) r += (key2[j] > ki);
        sbx[r][0] = bx[i][0]; sbx[r][1] = bx[i][1]; sbx[r][2] = bx[i][2]; sbx[r][3] = bx[i][3];
        ssc[r] = sc[i]; slb[r] = lb[i];
    }
    __syncthreads();
    for (int i = t; i < 300; i += 512)
        sar[i] = (sbx[i][2] - sbx[i][0]) * (sbx[i][3] - sbx[i][1]);
    __syncthreads();

    // export sorted pack
    for (int i = t; i < 300; i += 512) {
        float* p = sortf + i * 8;
        p[0] = sbx[i][0]; p[1] = sbx[i][1]; p[2] = sbx[i][2]; p[3] = sbx[i][3];
        p[4] = ssc[i]; p[5] = (float)slb[i]; p[6] = 0.f; p[7] = 0.f;
    }

    // supmat rows -> global; task = w*300 + i so a wave shares j-range (broadcast LDS reads)
    #pragma clang loop unroll(disable)
    for (int task = t; task < 1500; task += 512) {
        int w = task / 300, i = task - w * 300;
        float ax1 = sbx[i][0], ay1 = sbx[i][1], ax2 = sbx[i][2], ay2 = sbx[i][3], aa = sar[i];
        int al = slb[i];
        int jmax = (w == 4) ? 44 : 64;
        unsigned long long acc = 0ull;
        #pragma clang loop unroll(disable)
        for (int jb = 0; jb < jmax; jb++) {
            int j = w * 64 + jb;
            float xx1 = fmaxf(ax1, sbx[j][0]);
            float yy1 = fmaxf(ay1, sbx[j][1]);
            float xx2 = fminf(ax2, sbx[j][2]);
            float yy2 = fminf(ay2, sbx[j][3]);
            float iw = fmaxf(1e-10f, xx2 - xx1);
            float ih = fmaxf(1e-10f, yy2 - yy1);
            float inter = iw * ih;
            float iou = inter / (aa + sar[j] - inter);
            if (iou > 0.5f && al == slb[j]) acc |= (1ull << jb);
        }
        supG[i * 5 + w] = acc;
    }
}

// ---------------- K6: lane-parallel greedy NMS + output ----------------
// Lane l owns columns {l, 64+l, 128+l, 192+l, 256+l}. supmat is symmetric, so the
// column bits lane l needs from row i are bits (i&63) of supG[col][i>>6] -- i.e. the
// lane's OWN rows, preloaded into 15 registers m[w2][W] (W <= w2).
__global__ __launch_bounds__(256) void k_greedy(
    const float* __restrict__ sortf, const unsigned long long* __restrict__ supG,
    float* __restrict__ out)
{
    const int t = threadIdx.x;
    __shared__ unsigned char keepA[300];

    if (t < 64) {
        const int l = t;
        unsigned int validb = 0;
        float s0 = sortf[(l) * 8 + 4];
        float s1 = sortf[(64 + l) * 8 + 4];
        float s2 = sortf[(128 + l) * 8 + 4];
        float s3 = sortf[(192 + l) * 8 + 4];
        float s4 = (256 + l < 300) ? sortf[(256 + l) * 8 + 4] : 0.f;
        validb |= (s0 > 0.01f) ? 1u : 0u;
        validb |= (s1 > 0.01f) ? 2u : 0u;
        validb |= (s2 > 0.01f) ? 4u : 0u;
        validb |= (s3 > 0.01f) ? 8u : 0u;
        validb |= (s4 > 0.01f) ? 16u : 0u;

        const unsigned long long* g = supG;
        unsigned long long m00 = g[(l) * 5 + 0];
        unsigned long long m10 = g[(64 + l) * 5 + 0],  m11 = g[(64 + l) * 5 + 1];
        unsigned long long m20 = g[(128 + l) * 5 + 0], m21 = g[(128 + l) * 5 + 1], m22 = g[(128 + l) * 5 + 2];
        unsigned long long m30 = g[(192 + l) * 5 + 0], m31 = g[(192 + l) * 5 + 1], m32 = g[(192 + l) * 5 + 2], m33 = g[(192 + l) * 5 + 3];
        unsigned long long m40 = 0, m41 = 0, m42 = 0, m43 = 0, m44 = 0;
        if (256 + l < 300) {
            m40 = g[(256 + l) * 5 + 0]; m41 = g[(256 + l) * 5 + 1]; m42 = g[(256 + l) * 5 + 2];
            m43 = g[(256 + l) * 5 + 3]; m44 = g[(256 + l) * 5 + 4];
        }

        unsigned int supb = 0;

        #pragma clang loop unroll(disable)
        for (int b = 0; b < 64; b++) {           // word 0
            unsigned int x = __shfl(supb | ~validb, b);
            if (!((x >> 0) & 1u)) {
                unsigned int gt = (l > b) ? 1u : 0u;
                supb |= (((unsigned int)(m00 >> b) & gt)) << 0;
                supb |= (((unsigned int)(m10 >> b) & 1u)) << 1;
                supb |= (((unsigned int)(m20 >> b) & 1u)) << 2;
                supb |= (((unsigned int)(m30 >> b) & 1u)) << 3;
                supb |= (((unsigned int)(m40 >> b) & 1u)) << 4;
            }
        }
        #pragma clang loop unroll(disable)
        for (int b = 0; b < 64; b++) {           // word 1
            unsigned int x = __shfl(supb | ~validb, b);
            if (!((x >> 1) & 1u)) {
                unsigned int gt = (l > b) ? 1u : 0u;
                supb |= (((unsigned int)(m11 >> b) & gt)) << 1;
                supb |= (((unsigned int)(m21 >> b) & 1u)) << 2;
                supb |= (((unsigned int)(m31 >> b) & 1u)) << 3;
                supb |= (((unsigned int)(m41 >> b) & 1u)) << 4;
            }
        }
        #pragma clang loop unroll(disable)
        for (int b = 0; b < 64; b++) {           // word 2
            unsigned int x = __shfl(supb | ~validb, b);
            if (!((x >> 2) & 1u)) {
                unsigned int gt = (l > b) ? 1u : 0u;
                supb |= (((unsigned int)(m22 >> b) & gt)) << 2;
                supb |= (((unsigned int)(m32 >> b) & 1u)) << 3;
                supb |= (((unsigned int)(m42 >> b) & 1u)) << 4;
            }
        }
        #pragma clang loop unroll(disable)
        for (int b = 0; b < 64; b++) {           // word 3
            unsigned int x = __shfl(supb | ~validb, b);
            if (!((x >> 3) & 1u)) {
                unsigned int gt = (l > b) ? 1u : 0u;
                supb |= (((unsigned int)(m33 >> b) & gt)) << 3;
                supb |= (((unsigned int)(m43 >> b) & 1u)) << 4;
            }
        }
        #pragma clang loop unroll(disable)
        for (int b = 0; b < 44; b++) {           // word 4 (cols 256..299)
            unsigned int x = __shfl(supb | ~validb, b);
            if (!((x >> 4) & 1u)) {
                unsigned int gt = (l > b) ? 1u : 0u;
                supb |= (((unsigned int)(m44 >> b) & gt)) << 4;
            }
        }

        unsigned int kp = (~supb) & validb;
        keepA[l]       = (unsigned char)(kp & 1u);
        keepA[64 + l]  = (unsigned char)((kp >> 1) & 1u);
        keepA[128 + l] = (unsigned char)((kp >> 2) & 1u);
        keepA[192 + l] = (unsigned char)((kp >> 3) & 1u);
        if (256 + l < 300) keepA[256 + l] = (unsigned char)((kp >> 4) & 1u);
    }
    __syncthreads();

    #pragma clang loop unroll(disable)
    for (int i = t; i < 300; i += 256) {
        const float* p = sortf + i * 8;
        float kpf = keepA[i] ? 1.f : 0.f;
        out[i * 4 + 0] = p[0];
        out[i * 4 + 1] = p[1];
        out[i * 4 + 2] = p[2];
        out[i * 4 + 3] = p[3];
        out[1200 + i] = p[4] * kpf;
        out[1500 + i] = p[5];
        out[1800 + i] = kpf;
    }
}

// ---------------- launch ----------------
extern "C" void kernel_launch(void* const* d_in, const int* in_sizes, int n_in,
                              void* d_out, int out_size, void* d_ws, size_t ws_size,
                              hipStream_t stream)
{
    const float* obj0 = (const float*)d_in[0];
    const float* cls0 = (const float*)d_in[1];
    const float* reg0 = (const float*)d_in[2];
    const float* obj1 = (const float*)d_in[3];
    const float* cls1 = (const float*)d_in[4];
    const float* reg1 = (const float*)d_in[5];
    const float* obj2 = (const float*)d_in[6];
    const float* cls2 = (const float*)d_in[7];
    const float* reg2 = (const float*)d_in[8];

    char* ws = (char*)d_ws;
    unsigned int* hdr  = (unsigned int*)ws;                            // 256 B
    unsigned int* hist = (unsigned int*)(ws + 256);                    // 48 KB
    unsigned long long* surv = (unsigned long long*)(ws + 49408);      // 48 KB
    float* sortf = (float*)(ws + 98560);                               // 9.6 KB
    unsigned long long* supG = (unsigned long long*)(ws + 108544);     // 12 KB
    const size_t off = 131072;

    size_t avail = (ws_size > off) ? (ws_size - off) : 0;
    long long ents = (long long)(avail / 8);
    long long cap0 = ents * 16 / 21; if (cap0 > 6144000LL) cap0 = 6144000LL;
    long long cap1 = ents * 4 / 21;  if (cap1 > 1536000LL) cap1 = 1536000LL;
    long long cap2 = ents * 1 / 21;  if (cap2 > 384000LL)  cap2 = 384000LL;
    if (cap0 < 1) cap0 = 1; if (cap1 < 1) cap1 = 1; if (cap2 < 1) cap2 = 1;

    unsigned long long* buf0 = (unsigned long long*)(ws + off);
    unsigned long long* buf1 = buf0 + cap0;
    unsigned long long* buf2 = buf1 + cap1;

    k_init<<<1, 1024, 0, stream>>>(hdr, hist);
    k_score<0><<<789, 256, 0, stream>>>(obj0, cls0, obj1, cls1, obj2, cls2,
                                        hdr, hist, buf0, buf1, buf2,
                                        (int)cap0, (int)cap1, (int)cap2);
    k_score<1><<<789, 256, 0, stream>>>(obj0, cls0, obj1, cls1, obj2, cls2,
                                        hdr, hist, buf0, buf1, buf2,
                                        (int)cap0, (int)cap1, (int)cap2);
    k_scan<<<1, 192, 0, stream>>>(hdr, hist);
    k_compact<<<128, 256, 0, stream>>>(hdr, buf0, buf1, buf2,
                                       (int)cap0, (int)cap1, (int)cap2, surv);
    k_rank<<<1, 512, 0, stream>>>(hdr, surv, reg0, reg1, reg2, sortf, supG);
    k_greedy<<<1, 256, 0, stream>>>(sortf, supG, (float*)d_out);
}

// Round 6
// 214.872 us; speedup vs baseline: 1.7356x; 1.1688x over previous
//
#include <hip/hip_runtime.h>
#include <stdint.h>

// ---------------- constants ----------------
#define NCLS 20
#define STG_PER_WAVE 640
#define STG_TRIG 512
#define SURV_CAP 2048

__device__ __forceinline__ float sigm(float x) { return 1.0f / (1.0f + expf(-x)); }

// ---------------- K0: init ws ----------------
__global__ void k_init(unsigned int* hdr, unsigned int* hist) {
    int t = threadIdx.x;
    for (int i = t; i < 64; i += 1024) hdr[i] = 0u;
    for (int i = t; i < 3 * 4096; i += 1024) hist[i] = 0u;
}

// ---------------- K1/K2: streaming score pass ----------------
// hdr[0..2] main counts, hdr[4..6] fallback counts, hdr[12..14] survivor counts
template<int FB>
__global__ __launch_bounds__(256) void k_score(
    const float* __restrict__ obj0, const float* __restrict__ cls0,
    const float* __restrict__ obj1, const float* __restrict__ cls1,
    const float* __restrict__ obj2, const float* __restrict__ cls2,
    unsigned int* hdr, unsigned int* hist,
    unsigned long long* buf0, unsigned long long* buf1, unsigned long long* buf2,
    int cap0, int cap1, int cap2)
{
    int b = blockIdx.x;
    int L, tile, a, W;
    const float *obj, *cls; unsigned long long* gbuf; int cap;
    if (b < 600)      { L = 0; tile = b % 200;              a = b / 200; W = 320; obj = obj0; cls = cls0; gbuf = buf0; cap = cap0; }
    else if (b < 750) { int bb = b - 600; L = 1; tile = bb % 50; a = bb / 50; W = 160; obj = obj1; cls = cls1; gbuf = buf1; cap = cap1; }
    else              { int bb = b - 750; L = 2; tile = bb % 13; a = bb / 13; W = 80;  obj = obj2; cls = cls2; gbuf = buf2; cap = cap2; }
    const int P = W * W;
    if (FB) { if (hdr[L] >= 100u) return; }

    __shared__ unsigned long long stage[4 * STG_PER_WAVE];
    __shared__ unsigned int lhist[4096];
    __shared__ int wcnt[4];

    const int t = threadIdx.x;
    const int wid = t >> 6, lane = t & 63;
    for (int i = t; i < 4096; i += 256) lhist[i] = 0u;
    if (lane == 0) wcnt[wid] = 0;
    __syncthreads();

    unsigned long long* wstage = stage + wid * STG_PER_WAVE;
    const int p0 = tile * 512 + t * 2;
    const bool act = p0 < P;

    float so0 = 0.f, so1 = 0.f;
    if (act) {
        float2 ov = *(const float2*)(obj + (size_t)a * P + p0);
        so0 = sigm(ov.x); so1 = sigm(ov.y);
    }
    #pragma unroll
    for (int c = 0; c < NCLS; c++) {
        if (act) {
            float2 cv = *(const float2*)(cls + (size_t)(a * NCLS + c) * P + p0);
            float s0 = so0 * sigm(cv.x);
            float s1 = so1 * sigm(cv.y);
            #pragma unroll
            for (int q = 0; q < 2; q++) {
                float s = q ? s1 : s0;
                unsigned int bits = __float_as_uint(s);
                if (!FB && s >= 0.5f) {
                    unsigned int bin = (bits - 0x3F000000u) >> 11;
                    if (bin > 4095u) bin = 4095u;
                    atomicAdd(&lhist[bin], 1u);
                }
                bool take = FB ? (s <= 0.7f) : (s > 0.7f);
                if (take) {
                    unsigned int ti = (unsigned int)(((p0 + q) * 3 + a) * NCLS + c);
                    unsigned long long key =
                        ((unsigned long long)bits << 32) | (unsigned long long)(0xFFFFFFFFu - ti);
                    int pos = atomicAdd(&wcnt[wid], 1);
                    if (pos < STG_PER_WAVE) wstage[pos] = key;
                }
            }
        }
        if (wcnt[wid] >= STG_TRIG) {      // wave-uniform flush
            int n = wcnt[wid]; if (n > STG_PER_WAVE) n = STG_PER_WAVE;
            unsigned int base = 0;
            if (lane == 0) {
                if (FB) base = hdr[L] + atomicAdd(&hdr[4 + L], (unsigned int)n);
                else    base = atomicAdd(&hdr[L], (unsigned int)n);
            }
            base = __shfl(base, 0);
            for (int i = lane; i < n; i += 64) {
                unsigned int gp = base + i;
                if (gp < (unsigned int)cap) gbuf[gp] = wstage[i];
            }
            if (lane == 0) wcnt[wid] = 0;
        }
    }
    {   // final flush
        int n = wcnt[wid]; if (n > STG_PER_WAVE) n = STG_PER_WAVE;
        if (n > 0) {
            unsigned int base = 0;
            if (lane == 0) {
                if (FB) base = hdr[L] + atomicAdd(&hdr[4 + L], (unsigned int)n);
                else    base = atomicAdd(&hdr[L], (unsigned int)n);
            }
            base = __shfl(base, 0);
            for (int i = lane; i < n; i += 64) {
                unsigned int gp = base + i;
                if (gp < (unsigned int)cap) gbuf[gp] = wstage[i];
            }
        }
    }
    if (!FB) {
        __syncthreads();
        for (int i = t; i < 4096; i += 256) {
            unsigned int v = lhist[i];
            if (v) atomicAdd(&hist[L * 4096 + i], v);
        }
    }
}

// ---------------- K4: compact (each block redundantly computes Tsel first) ----------------
__global__ __launch_bounds__(256) void k_compact(unsigned int* hdr, const unsigned int* __restrict__ hist,
                          const unsigned long long* __restrict__ buf0,
                          const unsigned long long* __restrict__ buf1,
                          const unsigned long long* __restrict__ buf2,
                          int cap0, int cap1, int cap2,
                          unsigned long long* surv)
{
    __shared__ unsigned int tsel[3];
    const int t = threadIdx.x;
    const int lane = t & 63;
    if (t < 3) tsel[t] = 0u;
    __syncthreads();

    // redundant per-block threshold scan: wave L handles level L
    if (t < 192) {
        int L = t >> 6;
        const unsigned int* h = hist + L * 4096;
        unsigned int s = 0;
        for (int k = 0; k < 64; k++) s += h[4095 - (lane * 64 + k)];
        unsigned int incl = s;
        #pragma unroll
        for (int off = 1; off < 64; off <<= 1) {
            unsigned int u = __shfl_up(incl, off);
            if (lane >= off) incl += u;
        }
        unsigned int excl = incl - s;
        if (excl < 100u && incl >= 100u) {
            unsigned int cum = excl;
            for (int k = 0; k < 64; k++) {
                cum += h[4095 - (lane * 64 + k)];
                if (cum >= 100u) {
                    tsel[L] = 0x3F000000u + ((unsigned int)(4095 - (lane * 64 + k)) << 11);
                    break;
                }
            }
        }
    }
    __syncthreads();

    int gt = blockIdx.x * blockDim.x + t;
    int gstep = gridDim.x * blockDim.x;
    for (int L = 0; L < 3; L++) {
        const unsigned long long* buf = (L == 0) ? buf0 : (L == 1 ? buf1 : buf2);
        int cap = (L == 0) ? cap0 : (L == 1 ? cap1 : cap2);
        unsigned int cnt = hdr[L] + hdr[4 + L];
        int n = (int)((cnt < (unsigned int)cap) ? cnt : (unsigned int)cap);
        unsigned int ts = tsel[L];
        for (int i = gt; i < n; i += gstep) {
            unsigned long long k = buf[i];
            bool takeIt = (unsigned int)(k >> 32) >= ts;
            unsigned long long m = __ballot(takeIt);
            if (takeIt) {
                int lead = __ffsll((long long)m) - 1;
                int pref = __popcll(m & ((1ull << lane) - 1ull));
                unsigned int base = 0;
                if (lane == lead) base = atomicAdd(&hdr[12 + L], (unsigned int)__popcll(m));
                base = __shfl(base, lead);
                unsigned int pos = base + (unsigned int)pref;
                if (pos < SURV_CAP) surv[L * SURV_CAP + pos] = k;
            }
        }
    }
}

// ---------------- K5: rank-select + decode + sort -> sortf[300][8] ----------------
__global__ __launch_bounds__(512) void k_rank(
    const unsigned int* __restrict__ hdr,
    const unsigned long long* __restrict__ surv,
    const float* __restrict__ reg0, const float* __restrict__ reg1, const float* __restrict__ reg2,
    float* __restrict__ sortf)
{
    const int t = threadIdx.x;
    __shared__ unsigned long long svl[SURV_CAP];
    __shared__ unsigned long long topk[300];
    __shared__ float bx[300][4];
    __shared__ float sc[300];
    __shared__ int   lb[300];
    __shared__ unsigned long long key2[300];

    for (int i = t; i < 300; i += 512) topk[i] = 0ull;
    __syncthreads();

    // rank-select per level (keys unique)
    for (int L = 0; L < 3; L++) {
        int n = (int)hdr[12 + L]; if (n > SURV_CAP) n = SURV_CAP;
        const unsigned long long* sv = surv + L * SURV_CAP;
        for (int i = t; i < n; i += 512) svl[i] = sv[i];
        __syncthreads();
        for (int i = t; i < n; i += 512) {
            unsigned long long ki = svl[i];
            int r = 0;
            for (int j = 0; j < n; j++) r += (svl[j] > ki);
            if (r < 100) topk[L * 100 + r] = ki;
        }
        __syncthreads();
    }

    const int   Wl[3] = {320, 160, 80};
    const float Sl[3] = {8.f, 16.f, 32.f};
    const float AW[3][3] = {{12.f, 19.f, 40.f}, {36.f, 76.f, 72.f}, {142.f, 192.f, 459.f}};
    const float AH[3][3] = {{16.f, 36.f, 28.f}, {75.f, 55.f, 146.f}, {110.f, 243.f, 401.f}};

    // decode
    for (int i = t; i < 300; i += 512) {
        unsigned long long k = topk[i];
        int L = i / 100;
        float s = __uint_as_float((unsigned int)(k >> 32));
        unsigned int ti = 0xFFFFFFFFu - (unsigned int)k;
        float x1 = 0.f, y1 = 0.f, x2 = 0.f, y2 = 0.f; int c = 0;
        if (k != 0ull) {
            c = (int)(ti % NCLS);
            unsigned int na = ti / NCLS;
            int a = (int)(na % 3);
            int p = (int)(na / 3);
            int W = Wl[L]; int P = W * W;
            int px = p % W, py = p / W;
            const float* reg = (L == 0) ? reg0 : (L == 1 ? reg1 : reg2);
            float tx = reg[(a * 4 + 0) * P + p];
            float ty = reg[(a * 4 + 1) * P + p];
            float tw = reg[(a * 4 + 2) * P + p];
            float th = reg[(a * 4 + 3) * P + p];
            float st = Sl[L];
            float cx = (sigm(tx) * 3.0f - 1.5f + ((float)px + 0.5f)) * st;
            float cy = (sigm(ty) * 3.0f - 1.5f + ((float)py + 0.5f)) * st;
            float w = expf(tw) * AW[L][a];
            float h = expf(th) * AH[L][a];
            x1 = cx - 0.5f * w; y1 = cy - 0.5f * h; x2 = cx + 0.5f * w; y2 = cy + 0.5f * h;
        } else {
            s = 0.f;
        }
        bx[i][0] = x1; bx[i][1] = y1; bx[i][2] = x2; bx[i][3] = y2;
        sc[i] = s; lb[i] = c;
        key2[i] = (k & 0xFFFFFFFF00000000ull) | (unsigned long long)(299 - i);  // stable
    }
    __syncthreads();

    // sort by rank, write sorted pack straight to global
    for (int i = t; i < 300; i += 512) {
        unsigned long long ki = key2[i];
        int r = 0;
        for (int j = 0; j < 300; j++) r += (key2[j] > ki);
        float* p = sortf + r * 8;
        p[0] = bx[i][0]; p[1] = bx[i][1]; p[2] = bx[i][2]; p[3] = bx[i][3];
        p[4] = sc[i]; p[5] = (float)lb[i]; p[6] = 0.f; p[7] = 0.f;
    }
}

// ---------------- K5b: suppression matrix, 6 blocks x 256 ----------------
// task = w*300 + i (consecutive threads share the j-range -> broadcast LDS reads)
__global__ __launch_bounds__(256) void k_supmat(
    const float* __restrict__ sortf, unsigned long long* __restrict__ supG)
{
    __shared__ float sx1[300], sy1[300], sx2[300], sy2[300], sar[300];
    __shared__ int slb[300];
    const int t = threadIdx.x;
    for (int i = t; i < 300; i += 256) {
        float4 b = *(const float4*)(sortf + i * 8);
        sx1[i] = b.x; sy1[i] = b.y; sx2[i] = b.z; sy2[i] = b.w;
        sar[i] = (b.z - b.x) * (b.w - b.y);
        slb[i] = (int)sortf[i * 8 + 5];
    }
    __syncthreads();

    int task = blockIdx.x * 256 + t;
    if (task >= 1500) return;
    int w = task / 300, i = task - w * 300;
    float ax1 = sx1[i], ay1 = sy1[i], ax2 = sx2[i], ay2 = sy2[i], aa = sar[i];
    int al = slb[i];
    int jmax = (w == 4) ? 44 : 64;
    unsigned long long acc = 0ull;
    for (int jb = 0; jb < jmax; jb++) {
        int j = w * 64 + jb;
        float xx1 = fmaxf(ax1, sx1[j]);
        float yy1 = fmaxf(ay1, sy1[j]);
        float xx2 = fminf(ax2, sx2[j]);
        float yy2 = fminf(ay2, sy2[j]);
        float iw = fmaxf(1e-10f, xx2 - xx1);
        float ih = fmaxf(1e-10f, yy2 - yy1);
        float inter = iw * ih;
        float iou = inter / (aa + sar[j] - inter);
        if (iou > 0.5f && al == slb[j]) acc |= (1ull << jb);
    }
    supG[i * 5 + w] = acc;
}

// ---------------- K6: lane-parallel greedy NMS + output ----------------
// Lane l owns columns {l, 64+l, 128+l, 192+l, 256+l}; supmat symmetry lets each lane
// preload only its OWN rows (15 u64 regs).
__global__ __launch_bounds__(256) void k_greedy(
    const float* __restrict__ sortf, const unsigned long long* __restrict__ supG,
    float* __restrict__ out)
{
    const int t = threadIdx.x;
    __shared__ unsigned char keepA[300];

    if (t < 64) {
        const int l = t;
        unsigned int validb = 0;
        float s0 = sortf[(l) * 8 + 4];
        float s1 = sortf[(64 + l) * 8 + 4];
        float s2 = sortf[(128 + l) * 8 + 4];
        float s3 = sortf[(192 + l) * 8 + 4];
        float s4 = (256 + l < 300) ? sortf[(256 + l) * 8 + 4] : 0.f;
        validb |= (s0 > 0.01f) ? 1u : 0u;
        validb |= (s1 > 0.01f) ? 2u : 0u;
        validb |= (s2 > 0.01f) ? 4u : 0u;
        validb |= (s3 > 0.01f) ? 8u : 0u;
        validb |= (s4 > 0.01f) ? 16u : 0u;

        const unsigned long long* g = supG;
        unsigned long long m00 = g[(l) * 5 + 0];
        unsigned long long m10 = g[(64 + l) * 5 + 0],  m11 = g[(64 + l) * 5 + 1];
        unsigned long long m20 = g[(128 + l) * 5 + 0], m21 = g[(128 + l) * 5 + 1], m22 = g[(128 + l) * 5 + 2];
        unsigned long long m30 = g[(192 + l) * 5 + 0], m31 = g[(192 + l) * 5 + 1], m32 = g[(192 + l) * 5 + 2], m33 = g[(192 + l) * 5 + 3];
        unsigned long long m40 = 0, m41 = 0, m42 = 0, m43 = 0, m44 = 0;
        if (256 + l < 300) {
            m40 = g[(256 + l) * 5 + 0]; m41 = g[(256 + l) * 5 + 1]; m42 = g[(256 + l) * 5 + 2];
            m43 = g[(256 + l) * 5 + 3]; m44 = g[(256 + l) * 5 + 4];
        }

        unsigned int supb = 0;

        #pragma clang loop unroll(disable)
        for (int b = 0; b < 64; b++) {           // word 0
            unsigned int x = __shfl(supb | ~validb, b);
            if (!((x >> 0) & 1u)) {
                unsigned int gt = (l > b) ? 1u : 0u;
                supb |= (((unsigned int)(m00 >> b) & gt)) << 0;
                supb |= (((unsigned int)(m10 >> b) & 1u)) << 1;
                supb |= (((unsigned int)(m20 >> b) & 1u)) << 2;
                supb |= (((unsigned int)(m30 >> b) & 1u)) << 3;
                supb |= (((unsigned int)(m40 >> b) & 1u)) << 4;
            }
        }
        #pragma clang loop unroll(disable)
        for (int b = 0; b < 64; b++) {           // word 1
            unsigned int x = __shfl(supb | ~validb, b);
            if (!((x >> 1) & 1u)) {
                unsigned int gt = (l > b) ? 1u : 0u;
                supb |= (((unsigned int)(m11 >> b) & gt)) << 1;
                supb |= (((unsigned int)(m21 >> b) & 1u)) << 2;
                supb |= (((unsigned int)(m31 >> b) & 1u)) << 3;
                supb |= (((unsigned int)(m41 >> b) & 1u)) << 4;
            }
        }
        #pragma clang loop unroll(disable)
        for (int b = 0; b < 64; b++) {           // word 2
            unsigned int x = __shfl(supb | ~validb, b);
            if (!((x >> 2) & 1u)) {
                unsigned int gt = (l > b) ? 1u : 0u;
                supb |= (((unsigned int)(m22 >> b) & gt)) << 2;
                supb |= (((unsigned int)(m32 >> b) & 1u)) << 3;
                supb |= (((unsigned int)(m42 >> b) & 1u)) << 4;
            }
        }
        #pragma clang loop unroll(disable)
        for (int b = 0; b < 64; b++) {           // word 3
            unsigned int x = __shfl(supb | ~validb, b);
            if (!((x >> 3) & 1u)) {
                unsigned int gt = (l > b) ? 1u : 0u;
                supb |= (((unsigned int)(m33 >> b) & gt)) << 3;
                supb |= (((unsigned int)(m43 >> b) & 1u)) << 4;
            }
        }
        #pragma clang loop unroll(disable)
        for (int b = 0; b < 44; b++) {           // word 4 (cols 256..299)
            unsigned int x = __shfl(supb | ~validb, b);
            if (!((x >> 4) & 1u)) {
                unsigned int gt = (l > b) ? 1u : 0u;
                supb |= (((unsigned int)(m44 >> b) & gt)) << 4;
            }
        }

        unsigned int kp = (~supb) & validb;
        keepA[l]       = (unsigned char)(kp & 1u);
        keepA[64 + l]  = (unsigned char)((kp >> 1) & 1u);
        keepA[128 + l] = (unsigned char)((kp >> 2) & 1u);
        keepA[192 + l] = (unsigned char)((kp >> 3) & 1u);
        if (256 + l < 300) keepA[256 + l] = (unsigned char)((kp >> 4) & 1u);
    }
    __syncthreads();

    for (int i = t; i < 300; i += 256) {
        const float* p = sortf + i * 8;
        float kpf = keepA[i] ? 1.f : 0.f;
        out[i * 4 + 0] = p[0];
        out[i * 4 + 1] = p[1];
        out[i * 4 + 2] = p[2];
        out[i * 4 + 3] = p[3];
        out[1200 + i] = p[4] * kpf;
        out[1500 + i] = p[5];
        out[1800 + i] = kpf;
    }
}

// ---------------- launch ----------------
extern "C" void kernel_launch(void* const* d_in, const int* in_sizes, int n_in,
                              void* d_out, int out_size, void* d_ws, size_t ws_size,
                              hipStream_t stream)
{
    const float* obj0 = (const float*)d_in[0];
    const float* cls0 = (const float*)d_in[1];
    const float* reg0 = (const float*)d_in[2];
    const float* obj1 = (const float*)d_in[3];
    const float* cls1 = (const float*)d_in[4];
    const float* reg1 = (const float*)d_in[5];
    const float* obj2 = (const float*)d_in[6];
    const float* cls2 = (const float*)d_in[7];
    const float* reg2 = (const float*)d_in[8];

    char* ws = (char*)d_ws;
    unsigned int* hdr  = (unsigned int*)ws;                            // 256 B
    unsigned int* hist = (unsigned int*)(ws + 256);                    // 48 KB
    unsigned long long* surv = (unsigned long long*)(ws + 49408);      // 48 KB
    float* sortf = (float*)(ws + 98560);                               // 9.6 KB
    unsigned long long* supG = (unsigned long long*)(ws + 108544);     // 12 KB
    const size_t off = 131072;

    size_t avail = (ws_size > off) ? (ws_size - off) : 0;
    long long ents = (long long)(avail / 8);
    long long cap0 = ents * 16 / 21; if (cap0 > 6144000LL) cap0 = 6144000LL;
    long long cap1 = ents * 4 / 21;  if (cap1 > 1536000LL) cap1 = 1536000LL;
    long long cap2 = ents * 1 / 21;  if (cap2 > 384000LL)  cap2 = 384000LL;
    if (cap0 < 1) cap0 = 1; if (cap1 < 1) cap1 = 1; if (cap2 < 1) cap2 = 1;

    unsigned long long* buf0 = (unsigned long long*)(ws + off);
    unsigned long long* buf1 = buf0 + cap0;
    unsigned long long* buf2 = buf1 + cap1;

    k_init<<<1, 1024, 0, stream>>>(hdr, hist);
    k_score<0><<<789, 256, 0, stream>>>(obj0, cls0, obj1, cls1, obj2, cls2,
                                        hdr, hist, buf0, buf1, buf2,
                                        (int)cap0, (int)cap1, (int)cap2);
    k_score<1><<<789, 256, 0, stream>>>(obj0, cls0, obj1, cls1, obj2, cls2,
                                        hdr, hist, buf0, buf1, buf2,
                                        (int)cap0, (int)cap1, (int)cap2);
    k_compact<<<128, 256, 0, stream>>>(hdr, hist, buf0, buf1, buf2,
                                       (int)cap0, (int)cap1, (int)cap2, surv);
    k_rank<<<1, 512, 0, stream>>>(hdr, surv, reg0, reg1, reg2, sortf);
    k_supmat<<<6, 256, 0, stream>>>(sortf, supG);
    k_greedy<<<1, 256, 0, stream>>>(sortf, supG, (float*)d_out);
}